// Round 10
// baseline (475.484 us; speedup 1.0000x reference)
//
#include <hip/hip_runtime.h>
#include <math.h>

#define B_    16
#define C_    256
#define H_    200
#define W_    200
#define NBOX  100
#define HID   256
#define OUTK  7
#define ROI_DIM 12544        // C_ * 49
#define KP    37632          // 3 * ROI_DIM  (split-bf16 interleave: [ah,ah,al]x[bh,bl,bh])
#define NCLS  4

struct __attribute__((packed, aligned(4))) f2u { float x, y; };

typedef __attribute__((ext_vector_type(8))) short short8v;
typedef __attribute__((ext_vector_type(4))) float f32x4;

static __device__ __forceinline__ unsigned short f2bf(float f) {
  unsigned u = __float_as_uint(f);
  return (unsigned short)((u + 0x7FFFu + ((u >> 16) & 1u)) >> 16);   // RNE
}
static __device__ __forceinline__ float bf2f(unsigned short h) {
  return __uint_as_float(((unsigned)h) << 16);
}

// ---------------------------------------------------------------- K1: ROI align — channel-exclusive blocks, gather from L2-hot map
// Block = (image, channel): 512 threads / 8 waves own ONE 160KB channel map
// exclusively; each wave gathers 12-13 boxes' 7x7 bins (lane = bin). The map
// is pulled into L2 once and reused by all 100 boxes while hot (the 3.25x
// box-overlap reuse that box-major order scattered across time). 84KB LDS pad
// forces 1 block/CU -> per-XCD footprint 32x160KB ~= L2 size. No LDS data
// path, no barriers; per-lane register tables; 2-box software pipeline.
__global__ __launch_bounds__(512) void roi_pool_kernel(
    const float* __restrict__ feat, const float* __restrict__ boxes,
    unsigned short* __restrict__ Ap)
{
  __shared__ float pad_[21504];        // 84KB: occupancy governor (1 block/CU)
  int tid = threadIdx.x;
  if (tid == 0) { volatile float* vp = pad_; vp[0] = 0.0f; }

  int bid = blockIdx.x;
  int img = bid >> 8;
  int ch  = bid & 255;
  int wid = tid >> 6, lane = tid & 63;
  int l49 = lane < 49 ? lane : 0;
  int bi = l49 / 7, bj = l49 - bi * 7;
  float fbi = (float)bi, fbj = (float)bj;

  const float* fm = feat + ((size_t)img * C_ + ch) * (H_ * W_);
  const float* bxbase = boxes + (size_t)img * NBOX * 4;
  unsigned short* apbase = Ap + (size_t)img * NBOX * KP + (size_t)(ch * 49 + l49) * 3;

  int start = wid * 12 + min(wid, 4);  // waves 0-3: 13 boxes, 4-7: 12
  int cnt   = wid < 4 ? 13 : 12;

  auto mk = [&](int bn_l, int* off, float* wr, float* hx, float* lx) {
    const float* bx = bxbase + bn_l * 4;
    float x1 = bx[0] - 0.5f, y1 = bx[1] - 0.5f;
    float bw = (bx[2] - 0.5f - x1) * (1.0f / 7.0f);
    float bh = (bx[3] - 0.5f - y1) * (1.0f / 7.0f);
    int yrow[2]; float wy0[2], wy1[2];
    #pragma unroll
    for (int s = 0; s < 2; ++s) {
      float yy = y1 + (fbi + 0.25f + 0.5f * (float)s) * bh;
      float yc = fminf(fmaxf(yy, 0.0f), 199.0f);
      int y0 = min((int)yc, 198);          // yc>=0: trunc == floor
      float ly = yc - (float)y0;
      yrow[s] = y0 * W_;
      wy0[s] = 1.0f - ly; wy1[s] = ly;
    }
    int xcol[2];
    #pragma unroll
    for (int s = 0; s < 2; ++s) {
      float xx = x1 + (fbj + 0.25f + 0.5f * (float)s) * bw;
      float xc = fminf(fmaxf(xx, 0.0f), 199.0f);
      int x0 = min((int)xc, 198);
      lx[s] = xc - (float)x0;
      hx[s] = 1.0f - lx[s];
      xcol[s] = x0;
    }
    #pragma unroll
    for (int sy = 0; sy < 2; ++sy)
      #pragma unroll
      for (int sx = 0; sx < 2; ++sx) {
        int k = sy * 4 + sx * 2;
        off[k]     = yrow[sy] + xcol[sx];
        off[k + 1] = yrow[sy] + W_ + xcol[sx];
        wr[k]     = wy0[sy];
        wr[k + 1] = wy1[sy];
      }
  };
  auto ld8 = [&](const int* off, f2u* t) {
    #pragma unroll
    for (int k = 0; k < 8; ++k) t[k] = *(const f2u*)(fm + off[k]);
  };
  auto fin = [&](int bn_l, const f2u* t, const float* wr, const float* hx, const float* lx) {
    float sum = 0.0f;
    #pragma unroll
    for (int k = 0; k < 8; ++k) {
      int sx = (k >> 1) & 1;
      sum += wr[k] * (hx[sx] * t[k].x + lx[sx] * t[k].y);
    }
    if (lane < 49) {
      float sv = sum * 0.25f;
      unsigned short hi = f2bf(sv);
      unsigned short lo = f2bf(sv - bf2f(hi));
      unsigned short* pw = apbase + (size_t)bn_l * KP;
      pw[0] = hi; pw[1] = hi; pw[2] = lo;
    }
  };

  int offA[8], offB[8];
  float wrA[8], wrB[8], hxA[2], hxB[2], lxA[2], lxB[2];
  f2u tA[8], tB[8];

  mk(start, offA, wrA, hxA, lxA);
  ld8(offA, tA);
  int i = 0;
  for (; i + 2 <= cnt; i += 2) {       // 2-box ping-pong pipeline
    mk(start + i + 1, offB, wrB, hxB, lxB);
    ld8(offB, tB);
    fin(start + i, tA, wrA, hxA, lxA);
    if (i + 2 < cnt) {
      mk(start + i + 2, offA, wrA, hxA, lxA);
      ld8(offA, tA);
    }
    fin(start + i + 1, tB, wrB, hxB, lxB);
  }
  if (i < cnt) fin(start + i, tA, wrA, hxA, lxA);
}

// ---------------------------------------------------------------- K1b: w_roi -> split-bf16 B' [bh, bl, bh]
__global__ __launch_bounds__(256) void wconv_kernel(
    const float* __restrict__ w, unsigned short* __restrict__ Bp)
{
  int i = blockIdx.x * 256 + threadIdx.x;     // over 256*12544
  int n = i / ROI_DIM, k = i - n * ROI_DIM;
  float f = w[i];
  unsigned short hi = f2bf(f);
  unsigned short lo = f2bf(f - bf2f(hi));
  unsigned short* r = Bp + (size_t)n * KP + 3 * k;
  r[0] = hi; r[1] = lo; r[2] = hi;
}

// ---------------------------------------------------------------- K2: token init (bias)
__global__ __launch_bounds__(256) void token_init_kernel(
    const float* __restrict__ b_roi, float* __restrict__ tokens)
{
  int i = blockIdx.x * 256 + threadIdx.x;   // 409600 total
  tokens[i] = b_roi[i & 255];
}

// ---------------------------------------------------------------- K3: bf16 MFMA GEMM  tokens += A'(1600xKP) @ B'(256xKP)^T
#define GBM 64
#define GBN 128
#define GBK 64
#define KSP 28
#define KT  21        // (KP/GBK)/KSP = 588/28
__global__ __launch_bounds__(256) void gemm_kernel(
    const unsigned short* __restrict__ Ap,
    const unsigned short* __restrict__ Bp,
    float* __restrict__ Cc)
{
  __shared__ __align__(16) short As[GBM * GBK];   // [row][8 chunks x 8 bf16], swizzled
  __shared__ __align__(16) short Bs[GBN * GBK];

  int tid  = threadIdx.x;
  int lane = tid & 63;
  int w    = tid >> 6;
  int wr   = w >> 1, wc = w & 1;          // wave (wr,wc): rows wr*32, cols wc*64
  int m0 = blockIdx.x * GBM;
  int n0 = blockIdx.y * GBN;
  int kbase = blockIdx.z * (GBK * KT);

  f32x4 acc[2][4];
  #pragma unroll
  for (int mi = 0; mi < 2; ++mi)
    #pragma unroll
    for (int nj = 0; nj < 4; ++nj)
      acc[mi][nj] = (f32x4){0.f, 0.f, 0.f, 0.f};

  for (int kt = 0; kt < KT; ++kt) {
    int kg = kbase + kt * GBK;
    __syncthreads();                       // previous compute done before overwrite
    #pragma unroll
    for (int r = 0; r < 2; ++r) {          // stage A: 512 chunks of 16B
      int q = tid + r * 256;
      int row = q >> 3, c16 = q & 7;
      int kc16 = c16 ^ (row & 7);
      short8v v = *(const short8v*)(Ap + (size_t)(m0 + row) * KP + kg + kc16 * 8);
      *(short8v*)(As + row * GBK + c16 * 8) = v;
    }
    #pragma unroll
    for (int r = 0; r < 4; ++r) {          // stage B: 1024 chunks
      int q = tid + r * 256;
      int row = q >> 3, c16 = q & 7;
      int kc16 = c16 ^ (row & 7);
      short8v v = *(const short8v*)(Bp + (size_t)(n0 + row) * KP + kg + kc16 * 8);
      *(short8v*)(Bs + row * GBK + c16 * 8) = v;
    }
    __syncthreads();
    #pragma unroll
    for (int kk = 0; kk < 2; ++kk) {       // two K=32 steps per tile
      short8v af[2], bf[4];
      #pragma unroll
      for (int mi = 0; mi < 2; ++mi) {
        int row = wr * 32 + mi * 16 + (lane & 15);
        int c16 = (kk * 4 + (lane >> 4)) ^ (row & 7);
        af[mi] = *(const short8v*)(As + row * GBK + c16 * 8);
      }
      #pragma unroll
      for (int nj = 0; nj < 4; ++nj) {
        int row = wc * 64 + nj * 16 + (lane & 15);
        int c16 = (kk * 4 + (lane >> 4)) ^ (row & 7);
        bf[nj] = *(const short8v*)(Bs + row * GBK + c16 * 8);
      }
      #pragma unroll
      for (int mi = 0; mi < 2; ++mi)
        #pragma unroll
        for (int nj = 0; nj < 4; ++nj)
          acc[mi][nj] = __builtin_amdgcn_mfma_f32_16x16x32_bf16(
              af[mi], bf[nj], acc[mi][nj], 0, 0, 0);
    }
  }
  // epilogue: D col = lane&15, row = (lane>>4)*4 + reg
  int cn = lane & 15, rg = lane >> 4;
  #pragma unroll
  for (int mi = 0; mi < 2; ++mi)
    #pragma unroll
    for (int nj = 0; nj < 4; ++nj)
      #pragma unroll
      for (int r = 0; r < 4; ++r) {
        int row = m0 + wr * 32 + mi * 16 + rg * 4 + r;
        int col = n0 + wc * 64 + nj * 16 + cn;
        atomicAdd(&Cc[(size_t)row * HID + col], acc[mi][nj][r]);
      }
}

// ---------------------------------------------------------------- K4: attention + LN + MLP (one block per batch)
__global__ __launch_bounds__(256) void head_kernel(
    const float* __restrict__ tokens, const float* __restrict__ sev_q,
    const float* __restrict__ w_in,  const float* __restrict__ b_in,
    const float* __restrict__ w_out, const float* __restrict__ b_out,
    const float* __restrict__ ln_g,  const float* __restrict__ ln_b,
    const float* __restrict__ w1,    const float* __restrict__ b1,
    const float* __restrict__ w2,    const float* __restrict__ b2,
    float* __restrict__ outp)
{
  __shared__ float qh_s[256], qkv_s[1024], qkb_s[4];
  __shared__ float sc_s[400], att_s[400], tbar_s[1024];
  __shared__ float ctx_s[256], o_s[256], x_s[256], h1_s[256], red_s[8];
  int b = blockIdx.x, tid = threadIdx.x;
  const float* tok = tokens + (size_t)b * NBOX * HID;

  {
    const float* wq = w_in + (size_t)tid * HID;
    float a = 0.0f;
    for (int e = 0; e < HID; ++e) a += sev_q[e] * wq[e];
    qh_s[tid] = a + b_in[tid];
  }
  __syncthreads();
  if (tid < 4) {
    float a = 0.0f;
    for (int d = 0; d < 64; ++d) a += qh_s[tid * 64 + d] * b_in[256 + tid * 64 + d];
    qkb_s[tid] = a;
  }
  #pragma unroll
  for (int r = 0; r < 4; ++r) {
    int p = tid + r * 256;
    int h = p >> 8, e = p & 255;
    float a = 0.0f;
    for (int d = 0; d < 64; ++d)
      a += qh_s[h * 64 + d] * w_in[(size_t)(256 + h * 64 + d) * HID + e];
    qkv_s[p] = a;
  }
  __syncthreads();
  for (int p = tid; p < 4 * NBOX; p += 256) {
    int h = p / NBOX, t = p - h * NBOX;
    const float* tr = tok + (size_t)t * HID;
    const float* qv = qkv_s + h * 256;
    float a = 0.0f;
    for (int e = 0; e < HID; ++e) a += qv[e] * tr[e];
    sc_s[p] = (a + qkb_s[h]) * 0.125f;
  }
  __syncthreads();
  if (tid < 4) {
    float mx = -1e30f;
    for (int t = 0; t < NBOX; ++t) mx = fmaxf(mx, sc_s[tid * NBOX + t]);
    float sm = 0.0f;
    for (int t = 0; t < NBOX; ++t) {
      float e = expf(sc_s[tid * NBOX + t] - mx);
      att_s[tid * NBOX + t] = e; sm += e;
    }
    float inv = 1.0f / sm;
    for (int t = 0; t < NBOX; ++t) att_s[tid * NBOX + t] *= inv;
  }
  __syncthreads();
  #pragma unroll
  for (int r = 0; r < 4; ++r) {
    int p = tid + r * 256;
    int h = p >> 8, e = p & 255;
    float a = 0.0f;
    for (int t = 0; t < NBOX; ++t) a += att_s[h * NBOX + t] * tok[(size_t)t * HID + e];
    tbar_s[p] = a;
  }
  __syncthreads();
  {
    int h = tid >> 6;
    const float* wv = w_in + (size_t)(512 + tid) * HID;
    const float* tb = tbar_s + h * 256;
    float a = 0.0f;
    for (int e = 0; e < HID; ++e) a += tb[e] * wv[e];
    ctx_s[tid] = a + b_in[512 + tid];
  }
  __syncthreads();
  {
    const float* wo = w_out + (size_t)tid * HID;
    float a = 0.0f;
    for (int k = 0; k < HID; ++k) a += ctx_s[k] * wo[k];
    o_s[tid] = a + b_out[tid];
  }
  __syncthreads();
  {
    float v = o_s[tid];
    float s1 = v, s2 = v * v;
    #pragma unroll
    for (int off = 32; off > 0; off >>= 1) {
      s1 += __shfl_down(s1, off);
      s2 += __shfl_down(s2, off);
    }
    if ((tid & 63) == 0) { red_s[(tid >> 6) * 2] = s1; red_s[(tid >> 6) * 2 + 1] = s2; }
    __syncthreads();
    float sum = red_s[0] + red_s[2] + red_s[4] + red_s[6];
    float ssq = red_s[1] + red_s[3] + red_s[5] + red_s[7];
    float mu  = sum * (1.0f / 256.0f);
    float var = ssq * (1.0f / 256.0f) - mu * mu;
    float inv = rsqrtf(var + 1e-5f);
    x_s[tid] = (v - mu) * inv * ln_g[tid] + ln_b[tid];
  }
  __syncthreads();
  {
    const float* wr = w1 + (size_t)tid * HID;
    float a = 0.0f;
    for (int k = 0; k < HID; ++k) a += x_s[k] * wr[k];
    h1_s[tid] = fmaxf(a + b1[tid], 0.0f);
  }
  __syncthreads();
  if (tid < NCLS) {
    const float* wr = w2 + (size_t)tid * HID;
    float a = 0.0f;
    for (int k = 0; k < HID; ++k) a += h1_s[k] * wr[k];
    outp[b * NCLS + tid] = a + b2[tid];
  }
}

// ---------------------------------------------------------------- launch
extern "C" void kernel_launch(void* const* d_in, const int* in_sizes, int n_in,
                              void* d_out, int out_size, void* d_ws, size_t ws_size,
                              hipStream_t stream) {
  (void)in_sizes; (void)n_in; (void)out_size; (void)ws_size;
  const float* feat  = (const float*)d_in[0];
  const float* boxes = (const float*)d_in[1];
  const float* w_roi = (const float*)d_in[2];
  const float* b_roi = (const float*)d_in[3];
  const float* sev_q = (const float*)d_in[4];
  const float* w_in  = (const float*)d_in[5];
  const float* b_in  = (const float*)d_in[6];
  const float* w_out = (const float*)d_in[7];
  const float* b_out = (const float*)d_in[8];
  const float* ln_g  = (const float*)d_in[9];
  const float* ln_b  = (const float*)d_in[10];
  const float* w1    = (const float*)d_in[11];
  const float* b1    = (const float*)d_in[12];
  const float* w2    = (const float*)d_in[13];
  const float* b2    = (const float*)d_in[14];
  float* out = (float*)d_out;

  unsigned short* Ap = (unsigned short*)d_ws;            // 1600 x 37632 bf16-split
  unsigned short* Bp = Ap + (size_t)B_ * NBOX * KP;      // 256 x 37632
  float* tokens = (float*)(Bp + (size_t)HID * KP);       // 1600 x 256 f32

  roi_pool_kernel  <<<B_ * C_, 512, 0, stream>>>(feat, boxes, Ap);
  wconv_kernel     <<<(HID * ROI_DIM) / 256, 256, 0, stream>>>(w_roi, Bp);
  token_init_kernel<<<(B_ * NBOX * HID) / 256, 256, 0, stream>>>(b_roi, tokens);
  gemm_kernel      <<<dim3((B_ * NBOX) / GBM, HID / GBN, KSP), 256, 0, stream>>>(Ap, Bp, tokens);
  head_kernel      <<<B_, 256, 0, stream>>>(tokens, sev_q, w_in, b_in, w_out, b_out,
                                            ln_g, ln_b, w1, b1, w2, b2, out);
}

// Round 11
// 376.116 us; speedup vs baseline: 1.2642x; 1.2642x over previous
//
#include <hip/hip_runtime.h>
#include <math.h>

#define B_    16
#define C_    256
#define H_    200
#define W_    200
#define NBOX  100
#define HID   256
#define OUTK  7
#define ROI_DIM 12544        // C_ * 49
#define KP    37632          // 3 * ROI_DIM  (split-bf16 interleave: [ah,ah,al]x[bh,bl,bh])
#define NCLS  4

struct __attribute__((packed, aligned(4))) f2u { float x, y; };

typedef __attribute__((ext_vector_type(8))) short short8v;
typedef __attribute__((ext_vector_type(4))) float f32x4;

static __device__ __forceinline__ unsigned short f2bf(float f) {
  unsigned u = __float_as_uint(f);
  return (unsigned short)((u + 0x7FFFu + ((u >> 16) & 1u)) >> 16);   // RNE
}
static __device__ __forceinline__ float bf2f(unsigned short h) {
  return __uint_as_float(((unsigned)h) << 16);
}

static __device__ __forceinline__ void gload_lds4(const void* g, void* l) {
  __builtin_amdgcn_global_load_lds(
      (const __attribute__((address_space(1))) unsigned*)g,
      (__attribute__((address_space(3))) unsigned*)l, 4, 0, 0);
}

// ---------------------------------------------------------------- K1: ROI align — async LDS-DMA, double-buffered, 1-wave blocks (R7)
__global__ __launch_bounds__(64) void roi_pool_kernel(
    const float* __restrict__ feat, const float* __restrict__ boxes,
    unsigned short* __restrict__ Ap)
{
  constexpr int SPP = 66;
  __shared__ float tile[2][28][SPP];   // 14.8 KB, wave-private
  __shared__ int   rowoff_s[28];
  __shared__ int   ixs_s[14];
  __shared__ float flys_s[14], flxs_s[14];

  int raw = blockIdx.x;
  int g   = raw & 31;           // channel group: channels [g*8, g*8+8); g%8 == XCD slot
  int bn  = raw >> 5;           // 0..1599
  int b   = bn / NBOX;

  const float* bx = boxes + (size_t)bn * 4;
  float px1 = bx[0] - 0.5f, py1 = bx[1] - 0.5f;
  float px2 = bx[2] - 0.5f, py2 = bx[3] - 0.5f;
  float bh = (py2 - py1) * (1.0f / OUTK);
  float bw = (px2 - px1) * (1.0f / OUTK);

  int lane = threadIdx.x;
  if (lane < 14) {
    int i = lane >> 1, s = lane & 1;
    float yy = py1 + ((float)i + ((float)s + 0.5f) * 0.5f) * bh;
    float yc = fminf(fmaxf(yy, 0.0f), (float)(H_ - 1));
    int y0 = min((int)floorf(yc), H_ - 2);
    rowoff_s[2 * lane]     = y0 * W_;
    rowoff_s[2 * lane + 1] = y0 * W_ + W_;
    flys_s[lane] = yc - (float)y0;
  } else if (lane >= 16 && lane < 30) {
    int t = lane - 16;
    int j = t >> 1, s = t & 1;
    float xx = px1 + ((float)j + ((float)s + 0.5f) * 0.5f) * bw;
    float xc = fminf(fmaxf(xx, 0.0f), (float)(W_ - 1));
    int x0 = min((int)floorf(xc), W_ - 2);
    ixs_s[t]  = x0;
    flxs_s[t] = xc - (float)x0;
  }
  asm volatile("s_waitcnt lgkmcnt(0)" ::: "memory");   // same-wave table visibility

  int xlo  = ixs_s[0];
  int span = ixs_s[13] + 2 - xlo;      // <= 64
  bool ld  = lane < span;

  int voff[28];                        // per-lane global byte offsets
  #pragma unroll
  for (int r = 0; r < 28; ++r) voff[r] = (rowoff_s[r] + xlo + lane) * 4;

  // per-lane bin constants, reused across all 8 channels
  int l49 = lane < 49 ? lane : 0;
  int bi = l49 / 7, bj = l49 - bi * 7;
  float ly0 = flys_s[2 * bi],     hy0 = 1.0f - ly0;
  float ly1 = flys_s[2 * bi + 1], hy1 = 1.0f - ly1;
  float lx0 = flxs_s[2 * bj],     hx0 = 1.0f - lx0;
  float lx1 = flxs_s[2 * bj + 1], hx1 = 1.0f - lx1;
  int xo0 = ixs_s[2 * bj] - xlo;
  int xo1 = ixs_s[2 * bj + 1] - xlo;
  int r0  = 4 * bi;

  int c0 = g * 8;
  const char* fc = (const char*)(feat + (size_t)b * (C_ * H_ * W_) + (size_t)c0 * (H_ * W_));
  unsigned short* pw = Ap + (size_t)bn * KP + (size_t)(c0 * 49 + l49) * 3;

  if (ld) {                            // prologue: DMA channel 0 -> buf0
    #pragma unroll
    for (int r = 0; r < 28; ++r) gload_lds4(fc + voff[r], &tile[0][r][0]);
  }

  #pragma unroll 1
  for (int n = 0; n < 8; ++n) {
    if (n < 7) {                       // issue next channel's DMA -> other buffer
      const char* fn = fc + (size_t)(n + 1) * (H_ * W_ * 4);
      if (ld) {
        #pragma unroll
        for (int r = 0; r < 28; ++r) gload_lds4(fn + voff[r], &tile[(n + 1) & 1][r][0]);
      }
      asm volatile("s_waitcnt vmcnt(28)" ::: "memory");   // current channel ready
    } else {
      asm volatile("s_waitcnt vmcnt(0)" ::: "memory");
    }
    float (*T)[SPP] = tile[n & 1];
    if (lane < 49) {
      f2u a0 = *(const f2u*)&T[r0 + 0][xo0];
      f2u a1 = *(const f2u*)&T[r0 + 1][xo0];
      f2u b0 = *(const f2u*)&T[r0 + 0][xo1];
      f2u b1 = *(const f2u*)&T[r0 + 1][xo1];
      f2u c2 = *(const f2u*)&T[r0 + 2][xo0];
      f2u c3 = *(const f2u*)&T[r0 + 3][xo0];
      f2u d2 = *(const f2u*)&T[r0 + 2][xo1];
      f2u d3 = *(const f2u*)&T[r0 + 3][xo1];
      float sum = hy0 * (hx0 * a0.x + lx0 * a0.y) + ly0 * (hx0 * a1.x + lx0 * a1.y)
                + hy0 * (hx1 * b0.x + lx1 * b0.y) + ly0 * (hx1 * b1.x + lx1 * b1.y)
                + hy1 * (hx0 * c2.x + lx0 * c2.y) + ly1 * (hx0 * c3.x + lx0 * c3.y)
                + hy1 * (hx1 * d2.x + lx1 * d2.y) + ly1 * (hx1 * d3.x + lx1 * d3.y);
      float s = sum * 0.25f;
      unsigned short hi = f2bf(s);
      unsigned short lo = f2bf(s - bf2f(hi));
      pw[0] = hi; pw[1] = hi; pw[2] = lo;
    }
    pw += 49 * 3;
  }
}

// ---------------------------------------------------------------- K1b: w_roi -> split-bf16 B' [bh, bl, bh]
__global__ __launch_bounds__(256) void wconv_kernel(
    const float* __restrict__ w, unsigned short* __restrict__ Bp)
{
  int i = blockIdx.x * 256 + threadIdx.x;     // over 256*12544
  int n = i / ROI_DIM, k = i - n * ROI_DIM;
  float f = w[i];
  unsigned short hi = f2bf(f);
  unsigned short lo = f2bf(f - bf2f(hi));
  unsigned short* r = Bp + (size_t)n * KP + 3 * k;
  r[0] = hi; r[1] = lo; r[2] = hi;
}

// ---------------------------------------------------------------- K3: bf16 MFMA GEMM, full-N tile, partials (no atomics)
#define GBM 64
#define GBN 256
#define GBK 64
#define KSP 21
#define KT  28        // (KP/GBK)/KSP = 588/21
__global__ __launch_bounds__(256) void gemm_kernel(
    const unsigned short* __restrict__ Ap,
    const unsigned short* __restrict__ Bp,
    float* __restrict__ Cpart)
{
  __shared__ __align__(16) short As[GBM * GBK];   // 8 KB, swizzled chunks
  __shared__ __align__(16) short Bs[GBN * GBK];   // 32 KB

  int tid  = threadIdx.x;
  int lane = tid & 63;
  int w    = tid >> 6;
  int wr   = w >> 1, wc = w & 1;          // wave: rows wr*32, cols wc*128
  int m0 = blockIdx.x * GBM;
  int z  = blockIdx.y;
  int kbase = z * (GBK * KT);

  f32x4 acc[2][8];
  #pragma unroll
  for (int mi = 0; mi < 2; ++mi)
    #pragma unroll
    for (int nj = 0; nj < 8; ++nj)
      acc[mi][nj] = (f32x4){0.f, 0.f, 0.f, 0.f};

  for (int kt = 0; kt < KT; ++kt) {
    int kg = kbase + kt * GBK;
    __syncthreads();
    #pragma unroll
    for (int r = 0; r < 2; ++r) {          // stage A: 512 chunks of 16B
      int q = tid + r * 256;
      int row = q >> 3, c16 = q & 7;
      int kc16 = c16 ^ (row & 7);
      short8v v = *(const short8v*)(Ap + (size_t)(m0 + row) * KP + kg + kc16 * 8);
      *(short8v*)(As + row * GBK + c16 * 8) = v;
    }
    #pragma unroll
    for (int r = 0; r < 8; ++r) {          // stage B: 2048 chunks (all 256 rows)
      int q = tid + r * 256;
      int row = q >> 3, c16 = q & 7;
      int kc16 = c16 ^ (row & 7);
      short8v v = *(const short8v*)(Bp + (size_t)row * KP + kg + kc16 * 8);
      *(short8v*)(Bs + row * GBK + c16 * 8) = v;
    }
    __syncthreads();
    #pragma unroll
    for (int kk = 0; kk < 2; ++kk) {       // two K=32 steps per tile
      short8v af[2], bf[8];
      #pragma unroll
      for (int mi = 0; mi < 2; ++mi) {
        int row = wr * 32 + mi * 16 + (lane & 15);
        int c16 = (kk * 4 + (lane >> 4)) ^ (row & 7);
        af[mi] = *(const short8v*)(As + row * GBK + c16 * 8);
      }
      #pragma unroll
      for (int nj = 0; nj < 8; ++nj) {
        int row = wc * 128 + nj * 16 + (lane & 15);
        int c16 = (kk * 4 + (lane >> 4)) ^ (row & 7);
        bf[nj] = *(const short8v*)(Bs + row * GBK + c16 * 8);
      }
      #pragma unroll
      for (int mi = 0; mi < 2; ++mi)
        #pragma unroll
        for (int nj = 0; nj < 8; ++nj)
          acc[mi][nj] = __builtin_amdgcn_mfma_f32_16x16x32_bf16(
              af[mi], bf[nj], acc[mi][nj], 0, 0, 0);
    }
  }
  // epilogue: plain stores to partial buffer (D col=lane&15, row=(lane>>4)*4+reg)
  float* part = Cpart + (size_t)z * (B_ * NBOX * HID);
  int cn = lane & 15, rg = lane >> 4;
  #pragma unroll
  for (int mi = 0; mi < 2; ++mi)
    #pragma unroll
    for (int nj = 0; nj < 8; ++nj)
      #pragma unroll
      for (int r = 0; r < 4; ++r) {
        int row = m0 + wr * 32 + mi * 16 + rg * 4 + r;
        int col = wc * 128 + nj * 16 + cn;
        part[(size_t)row * HID + col] = acc[mi][nj][r];
      }
}

// ---------------------------------------------------------------- K3b: tokens = bias + sum of partials
__global__ __launch_bounds__(256) void reduce_kernel(
    const float* __restrict__ Cpart, const float* __restrict__ b_roi,
    float* __restrict__ tokens)
{
  int i = blockIdx.x * 256 + threadIdx.x;   // 409600
  float a = b_roi[i & 255];
  #pragma unroll
  for (int z = 0; z < KSP; ++z) a += Cpart[(size_t)z * (B_ * NBOX * HID) + i];
  tokens[i] = a;
}

// ---------------------------------------------------------------- K4a: attention per (batch, head) -> ctx
__global__ __launch_bounds__(256) void attn_kernel(
    const float* __restrict__ tokens, const float* __restrict__ sev_q,
    const float* __restrict__ w_in,  const float* __restrict__ b_in,
    float* __restrict__ ctx)
{
  __shared__ float qh_s[64], qkv_s[256], att_s[128], tbar_s[256], red_s[2];
  int bh = blockIdx.x;
  int b = bh >> 2, h = bh & 3;
  int tid = threadIdx.x;
  const float* tok = tokens + (size_t)b * NBOX * HID;

  if (tid < 64) {                      // qh[d] = sev_q . Wq[h*64+d] + bq
    const float* wq = w_in + (size_t)(h * 64 + tid) * HID;
    float a = 0.0f;
    for (int e = 0; e < HID; ++e) a += sev_q[e] * wq[e];
    qh_s[tid] = a + b_in[h * 64 + tid];
  }
  __syncthreads();
  {                                    // qkv[e] = sum_d qh[d] * Wk[h*64+d][e]
    float a = 0.0f;
    for (int d = 0; d < 64; ++d)
      a += qh_s[d] * w_in[(size_t)(256 + h * 64 + d) * HID + tid];
    qkv_s[tid] = a;
  }
  if (tid == 0) {                      // qkb
    float a = 0.0f;
    for (int d = 0; d < 64; ++d) a += qh_s[d] * b_in[256 + h * 64 + d];
    red_s[0] = a;
  }
  __syncthreads();
  if (tid < NBOX) {                    // scores
    const float4* tr = (const float4*)(tok + (size_t)tid * HID);
    const float4* qv = (const float4*)qkv_s;
    float a = 0.0f;
    for (int e = 0; e < 64; ++e) {
      float4 t4 = tr[e], q4 = qv[e];
      a += t4.x * q4.x + t4.y * q4.y + t4.z * q4.z + t4.w * q4.w;
    }
    att_s[tid] = (a + red_s[0]) * 0.125f;
  }
  __syncthreads();
  if (tid == 0) {                      // softmax (serial; 100 elems)
    float mx = -1e30f;
    for (int t = 0; t < NBOX; ++t) mx = fmaxf(mx, att_s[t]);
    float sm = 0.0f;
    for (int t = 0; t < NBOX; ++t) { float e = expf(att_s[t] - mx); att_s[t] = e; sm += e; }
    red_s[1] = 1.0f / sm;
  }
  __syncthreads();
  {                                    // tbar[e] = inv * sum_t att[t]*tok[t][e]
    float a = 0.0f;
    for (int t = 0; t < NBOX; ++t) a += att_s[t] * tok[(size_t)t * HID + tid];
    tbar_s[tid] = a * red_s[1];
  }
  __syncthreads();
  if (tid < 64) {                      // ctx[h*64+d] = tbar . Wv[h*64+d] + bv
    const float* wv = w_in + (size_t)(512 + h * 64 + tid) * HID;
    float a = 0.0f;
    for (int e = 0; e < HID; ++e) a += tbar_s[e] * wv[e];
    ctx[(size_t)b * HID + h * 64 + tid] = a + b_in[512 + h * 64 + tid];
  }
}

// ---------------------------------------------------------------- K4b: Wout + LayerNorm + MLP per batch
__global__ __launch_bounds__(256) void mlp_kernel(
    const float* __restrict__ ctx,
    const float* __restrict__ w_out, const float* __restrict__ b_out,
    const float* __restrict__ ln_g,  const float* __restrict__ ln_b,
    const float* __restrict__ w1,    const float* __restrict__ b1,
    const float* __restrict__ w2,    const float* __restrict__ b2,
    float* __restrict__ outp)
{
  __shared__ float o_s[256], x_s[256], h1_s[256], red_s[8];
  int b = blockIdx.x, tid = threadIdx.x;
  const float* cx = ctx + (size_t)b * HID;
  {
    const float* wo = w_out + (size_t)tid * HID;
    float a = 0.0f;
    for (int k = 0; k < HID; ++k) a += cx[k] * wo[k];
    o_s[tid] = a + b_out[tid];
  }
  __syncthreads();
  {
    float v = o_s[tid];
    float s1 = v, s2 = v * v;
    #pragma unroll
    for (int off = 32; off > 0; off >>= 1) {
      s1 += __shfl_down(s1, off);
      s2 += __shfl_down(s2, off);
    }
    if ((tid & 63) == 0) { red_s[(tid >> 6) * 2] = s1; red_s[(tid >> 6) * 2 + 1] = s2; }
    __syncthreads();
    float sum = red_s[0] + red_s[2] + red_s[4] + red_s[6];
    float ssq = red_s[1] + red_s[3] + red_s[5] + red_s[7];
    float mu  = sum * (1.0f / 256.0f);
    float var = ssq * (1.0f / 256.0f) - mu * mu;
    float inv = rsqrtf(var + 1e-5f);
    x_s[tid] = (v - mu) * inv * ln_g[tid] + ln_b[tid];
  }
  __syncthreads();
  {
    const float* wr = w1 + (size_t)tid * HID;
    float a = 0.0f;
    for (int k = 0; k < HID; ++k) a += x_s[k] * wr[k];
    h1_s[tid] = fmaxf(a + b1[tid], 0.0f);
  }
  __syncthreads();
  if (tid < NCLS) {
    const float* wr = w2 + (size_t)tid * HID;
    float a = 0.0f;
    for (int k = 0; k < HID; ++k) a += h1_s[k] * wr[k];
    outp[b * NCLS + tid] = a + b2[tid];
  }
}

// ---------------------------------------------------------------- launch
extern "C" void kernel_launch(void* const* d_in, const int* in_sizes, int n_in,
                              void* d_out, int out_size, void* d_ws, size_t ws_size,
                              hipStream_t stream) {
  (void)in_sizes; (void)n_in; (void)out_size; (void)ws_size;
  const float* feat  = (const float*)d_in[0];
  const float* boxes = (const float*)d_in[1];
  const float* w_roi = (const float*)d_in[2];
  const float* b_roi = (const float*)d_in[3];
  const float* sev_q = (const float*)d_in[4];
  const float* w_in  = (const float*)d_in[5];
  const float* b_in  = (const float*)d_in[6];
  const float* w_out = (const float*)d_in[7];
  const float* b_out = (const float*)d_in[8];
  const float* ln_g  = (const float*)d_in[9];
  const float* ln_b  = (const float*)d_in[10];
  const float* w1    = (const float*)d_in[11];
  const float* b1    = (const float*)d_in[12];
  const float* w2    = (const float*)d_in[13];
  const float* b2    = (const float*)d_in[14];
  float* out = (float*)d_out;

  unsigned short* Ap = (unsigned short*)d_ws;            // 1600 x 37632 bf16-split
  unsigned short* Bp = Ap + (size_t)B_ * NBOX * KP;      // 256 x 37632
  float* Cpart  = (float*)(Bp + (size_t)HID * KP);       // KSP x 1600 x 256 f32
  float* tokens = Cpart + (size_t)KSP * B_ * NBOX * HID; // 1600 x 256 f32
  float* ctx    = tokens + (size_t)B_ * NBOX * HID;      // 16 x 256 f32

  roi_pool_kernel<<<B_ * NBOX * 32, 64, 0, stream>>>(feat, boxes, Ap);
  wconv_kernel   <<<(HID * ROI_DIM) / 256, 256, 0, stream>>>(w_roi, Bp);
  gemm_kernel    <<<dim3((B_ * NBOX) / GBM, KSP), 256, 0, stream>>>(Ap, Bp, Cpart);
  reduce_kernel  <<<(B_ * NBOX * HID) / 256, 256, 0, stream>>>(Cpart, b_roi, tokens);
  attn_kernel    <<<B_ * 4, 256, 0, stream>>>(tokens, sev_q, w_in, b_in, ctx);
  mlp_kernel     <<<B_, 256, 0, stream>>>(ctx, w_out, b_out, ln_g, ln_b,
                                          w1, b1, w2, b2, out);
}